// Round 7
// baseline (472.802 us; speedup 1.0000x reference)
//
#include <hip/hip_runtime.h>
#include <hip/hip_bf16.h>
#include <hip/hip_fp16.h>

// ---------------- problem constants ----------------
constexpr int GT = 32768;          // B*T frames
constexpr int TSEQ = 32;

typedef _Float16 h2 __attribute__((ext_vector_type(2)));

#if defined(__has_builtin)
#if __has_builtin(__builtin_amdgcn_fdot2)
#define FDOT2(a, b, c) __builtin_amdgcn_fdot2((a), (b), (c), false)
#endif
#endif
#ifndef FDOT2
#define FDOT2(a, b, c) fmaf((float)(a).x, (float)(b).x, fmaf((float)(a).y, (float)(b).y, (c)))
#endif

__device__ __forceinline__ h2 pack2(float a, float b) {
  h2 v; v.x = (_Float16)a; v.y = (_Float16)b; return v;
}

// ---------------- workspace layout (4-byte slots; wsh = h2 view, ws = f32 view) -----
constexpr size_t OBS_T  = 0;
constexpr size_t POOL1H = 13107200;
constexpr size_t FEATSH = 19660800;
constexpr size_t GX     = 0;
constexpr size_t WB     = 26214400;
constexpr size_t W_C1   = WB + 0;           // 576  fp32: conv1 wT [36][16]
constexpr size_t W_C2H  = WB + 576;         // 2304 h2: [(ci2*9+t9)][32 co]
constexpr size_t W_F1H  = WB + 2880;        // 8192 h2: [q=co2*4+pos][128 j], BN folded
constexpr size_t B_F1   = WB + 11072;       // 128 fp32
constexpr size_t W_F2H  = WB + 11200;       // 4096 h2: [k2][64 j], BN folded
constexpr size_t B_F2   = WB + 15296;       // 64 fp32
constexpr size_t W_ENCXH= WB + 15360;       // 16384 h2: [k2][512 r], rows r=u*4+gate
constexpr size_t W_ENCHH= WB + 31744;       // 32768 h2: [k2][512 r]
constexpr size_t B_ENC  = WB + 64512;       // 512 fp32
constexpr size_t W_DECH = WB + 65024;       // 32768 h2: (dec_w_ih+dec_w_hh) [k2][512]
constexpr size_t B_DEC  = WB + 97792;       // 512 fp32

__device__ __forceinline__ float sigf(float x)  { return 1.f / (1.f + __expf(-x)); }
__device__ __forceinline__ float tanhfast(float x) { return 1.f - 2.f / (__expf(2.f * x) + 1.f); }

// ---------------- setup: transpose/fold/f16-pack weights (98304 items) ----------
__global__ __launch_bounds__(256) void k_setup(
    const float* __restrict__ c1w, const float* __restrict__ c2w,
    const float* __restrict__ f1w, const float* __restrict__ f1b,
    const float* __restrict__ g1, const float* __restrict__ be1,
    const float* __restrict__ m1, const float* __restrict__ v1,
    const float* __restrict__ f2w, const float* __restrict__ f2b,
    const float* __restrict__ g2, const float* __restrict__ be2,
    const float* __restrict__ m2, const float* __restrict__ v2,
    const float* __restrict__ ewih, const float* __restrict__ ewhh, const float* __restrict__ eb,
    const float* __restrict__ dwih, const float* __restrict__ dwhh, const float* __restrict__ db,
    float* __restrict__ ws) {
  h2* wsh = (h2*)ws;
  long i = (long)blockIdx.x * 256 + threadIdx.x;
  if (i < 576)  { int c = i & 15, r = i >> 4; ws[W_C1 + i] = c1w[c * 36 + r]; return; }
  i -= 576;
  if (i < 2304) { int co = i & 31, q = i >> 5; int ci2 = q / 9, t9 = q % 9;
    wsh[W_C2H + i] = pack2(c2w[co * 144 + (2 * ci2) * 9 + t9],
                           c2w[co * 144 + (2 * ci2 + 1) * 9 + t9]); return; }
  i -= 2304;
  if (i < 8192) { int j = i & 127, q = i >> 7; int co2 = q >> 2, pos = q & 3;
    float s = g1[j] * rsqrtf(v1[j] + 1e-5f);
    wsh[W_F1H + i] = pack2(f1w[j * 128 + 8 * co2 + pos] * s,
                           f1w[j * 128 + 8 * co2 + 4 + pos] * s); return; }
  i -= 8192;
  if (i < 128) { int j = i; float s = g1[j] * rsqrtf(v1[j] + 1e-5f);
    ws[B_F1 + i] = (f1b[j] - m1[j]) * s + be1[j]; return; }
  i -= 128;
  if (i < 4096) { int j = i & 63, k2 = i >> 6;
    float s = g2[j] * rsqrtf(v2[j] + 1e-5f);
    wsh[W_F2H + i] = pack2(f2w[j * 128 + 2 * k2] * s,
                           f2w[j * 128 + 2 * k2 + 1] * s); return; }
  i -= 4096;
  if (i < 64) { int j = i; float s = g2[j] * rsqrtf(v2[j] + 1e-5f);
    ws[B_F2 + i] = (f2b[j] - m2[j]) * s + be2[j]; return; }
  i -= 64;
  if (i < 16384) { int r = i & 511, k2 = i >> 9;
    int u = r >> 2, gt = r & 3, jr = gt * 128 + u;
    wsh[W_ENCXH + i] = pack2(ewih[jr * 64 + 2 * k2], ewih[jr * 64 + 2 * k2 + 1]); return; }
  i -= 16384;
  if (i < 32768) { int r = i & 511, k2 = i >> 9;
    int u = r >> 2, gt = r & 3, jr = gt * 128 + u;
    wsh[W_ENCHH + i] = pack2(ewhh[jr * 128 + 2 * k2], ewhh[jr * 128 + 2 * k2 + 1]); return; }
  i -= 32768;
  if (i < 512) { int u = i >> 2, gt = i & 3; ws[B_ENC + i] = eb[gt * 128 + u]; return; }
  i -= 512;
  if (i < 32768) { int r = i & 511, k2 = i >> 9;
    int u = r >> 2, gt = r & 3, jr = gt * 128 + u;
    wsh[W_DECH + i] = pack2(dwih[jr * 128 + 2 * k2] + dwhh[jr * 128 + 2 * k2],
                            dwih[jr * 128 + 2 * k2 + 1] + dwhh[jr * 128 + 2 * k2 + 1]); return; }
  i -= 32768;
  if (i < 512) { int u = i >> 2, gt = i & 3; ws[B_DEC + i] = db[gt * 128 + u]; return; }
}

// ---------------- transpose obs [b][tp] -> obsT [p][t][b], float4 loads ----------------
__global__ __launch_bounds__(256) void k_transpose(const float* __restrict__ obs,
                                                   float* __restrict__ obsT) {
  __shared__ float tile[64][65];
  int tp0 = blockIdx.x * 64;
  int b0  = blockIdx.y * 64;
  int q     = threadIdx.x & 15;
  int rbase = threadIdx.x >> 4;
  #pragma unroll
  for (int rr = 0; rr < 4; ++rr) {
    int row = rbase + rr * 16;
    const float4 v = *(const float4*)(obs + (size_t)(b0 + row) * 12800 + tp0 + q * 4);
    tile[row][q * 4 + 0] = v.x;
    tile[row][q * 4 + 1] = v.y;
    tile[row][q * 4 + 2] = v.z;
    tile[row][q * 4 + 3] = v.w;
  }
  __syncthreads();
  int lane = threadIdx.x & 63;
  int grp  = threadIdx.x >> 6;
  for (int cc = 0; cc < 16; ++cc) {
    int col = grp * 16 + cc;
    int tp = tp0 + col;
    int t = tp / 400, p = tp % 400;
    obsT[(size_t)p * GT + t * 1024 + b0 + lane] = tile[lane][col];
  }
}

// ---------------- conv1 (4->16, fp32 math) + relu + maxpool2; writes f16 co-pairs ----
__global__ __launch_bounds__(256) void k_conv1(const float* __restrict__ obsT,
                                               const float* __restrict__ wT,
                                               const float* __restrict__ bias,
                                               h2* __restrict__ pool1h) {
  int g = blockIdx.x * 256 + threadIdx.x;
  int pos = blockIdx.y;
  int py = pos / 5, px = pos % 5;
  float acc[4][16];
  #pragma unroll
  for (int s = 0; s < 4; ++s)
    #pragma unroll
    for (int c = 0; c < 16; ++c) acc[s][c] = 0.f;

  #pragma unroll 1
  for (int ci = 0; ci < 4; ++ci) {
    float p[16];
    #pragma unroll
    for (int r = 0; r < 4; ++r) {
      int iy = 2 * py + r - 1;
      #pragma unroll
      for (int cx = 0; cx < 4; ++cx) {
        int ix = 2 * px + cx - 1;
        bool ok = ((unsigned)iy < 10u) && ((unsigned)ix < 10u);   // wave-uniform
        p[r * 4 + cx] = ok ? obsT[(size_t)(ci * 100 + iy * 10 + ix) * GT + g] : 0.f;
      }
    }
    #pragma unroll
    for (int t9 = 0; t9 < 9; ++t9) {
      int ky = t9 / 3, kx = t9 % 3;
      const float* w = wT + ((ci * 9 + t9) << 4);
      float wv[16];
      #pragma unroll
      for (int c = 0; c < 16; ++c) wv[c] = w[c];
      #pragma unroll
      for (int dy = 0; dy < 2; ++dy)
        #pragma unroll
        for (int dx = 0; dx < 2; ++dx) {
          float xv = p[(dy + ky) * 4 + (dx + kx)];
          #pragma unroll
          for (int c = 0; c < 16; ++c)
            acc[dy * 2 + dx][c] = fmaf(wv[c], xv, acc[dy * 2 + dx][c]);
        }
    }
  }
  float m[16];
  #pragma unroll
  for (int c = 0; c < 16; ++c) {
    float v = fmaxf(fmaxf(acc[0][c], acc[1][c]), fmaxf(acc[2][c], acc[3][c]));
    m[c] = fmaxf(v + bias[c], 0.f);
  }
  #pragma unroll
  for (int c2 = 0; c2 < 8; ++c2)
    pool1h[(size_t)(c2 * 25 + pos) * GT + g] = pack2(m[2 * c2], m[2 * c2 + 1]);
}

// ---------------- fused conv2 + fc1 + fc2 (R4 config — best measured: 99us) ----------
// 1024 blocks x 256 threads, launch_bounds(256,4). Block = 32 frames x 8 slices.
__global__ __launch_bounds__(256, 4) void k_cfx(
    const h2* __restrict__ pool1h,
    const h2* __restrict__ wc2, const float* __restrict__ c2b,
    const h2* __restrict__ wf1, const float* __restrict__ bf1,
    const h2* __restrict__ wf2, const float* __restrict__ bf2,
    h2* __restrict__ featsh) {
  const int tid = threadIdx.x;
  const int fr  = tid & 31;
  const int sl  = tid >> 5;           // 0..7
  const int g   = blockIdx.x * 32 + fr;
  const int pos = sl & 3;             // pooled pos 0..3
  const int ho  = sl >> 2;            // co half (16 channels)

  __shared__ h2 xbuf[32 * 65];      // conv2 out pairs, [fr][q=co2*4+pos], stride 65
  __shared__ h2 y1buf[32 * 65];     // fc1 out pairs,   [fr][jp],          stride 65

  // ---------- phase 1: conv2 at pooled pos, co-half ho ----------
  const int py = pos >> 1, px = pos & 1;
  const h2 hz = pack2(0.f, 0.f);
  float acc[4][16];
  #pragma unroll
  for (int s = 0; s < 4; ++s)
    #pragma unroll
    for (int c = 0; c < 16; ++c) acc[s][c] = 0.f;

  #pragma unroll 1
  for (int ci2 = 0; ci2 < 8; ++ci2) {
    h2 p[16];
    #pragma unroll
    for (int r = 0; r < 4; ++r) {
      int iy = 2 * py + r - 1;
      #pragma unroll
      for (int cx = 0; cx < 4; ++cx) {
        int ix = 2 * px + cx - 1;
        bool ok = ((unsigned)iy < 5u) && ((unsigned)ix < 5u);   // half-wave-uniform
        p[r * 4 + cx] = ok ? pool1h[(size_t)(ci2 * 25 + iy * 5 + ix) * GT + g] : hz;
      }
    }
    #pragma unroll
    for (int t9 = 0; t9 < 9; ++t9) {
      int ky = t9 / 3, kx = t9 % 3;
      const h2* w = wc2 + (ci2 * 9 + t9) * 32 + ho * 16;
      h2 wv[16];
      #pragma unroll
      for (int u = 0; u < 4; ++u) *(uint4*)&wv[u * 4] = *(const uint4*)&w[u * 4];
      #pragma unroll
      for (int dy = 0; dy < 2; ++dy)
        #pragma unroll
        for (int dx = 0; dx < 2; ++dx) {
          h2 xv = p[(dy + ky) * 4 + (dx + kx)];
          #pragma unroll
          for (int c = 0; c < 16; ++c)
            acc[dy * 2 + dx][c] = FDOT2(xv, wv[c], acc[dy * 2 + dx][c]);
        }
    }
  }
  #pragma unroll
  for (int c2 = 0; c2 < 8; ++c2) {
    float va = fmaxf(fmaxf(acc[0][2 * c2], acc[1][2 * c2]),
                     fmaxf(acc[2][2 * c2], acc[3][2 * c2]));
    float vb = fmaxf(fmaxf(acc[0][2 * c2 + 1], acc[1][2 * c2 + 1]),
                     fmaxf(acc[2][2 * c2 + 1], acc[3][2 * c2 + 1]));
    float a = fmaxf(va + c2b[ho * 16 + 2 * c2], 0.f);
    float b = fmaxf(vb + c2b[ho * 16 + 2 * c2 + 1], 0.f);
    int q = (ho * 8 + c2) * 4 + pos;       // co2*4 + pos
    xbuf[fr * 65 + q] = pack2(a, b);
  }
  __syncthreads();

  // ---------- phase 2: fc1, j in [sl*16, sl*16+16) ----------
  {
    float acc1[16];
    #pragma unroll
    for (int c = 0; c < 16; ++c) acc1[c] = 0.f;
    #pragma unroll 2
    for (int q = 0; q < 64; ++q) {
      h2 xv = xbuf[fr * 65 + q];            // scalar LDS read, conflict-free
      const h2* w = wf1 + q * 128 + sl * 16;
      h2 wv[16];
      #pragma unroll
      for (int u = 0; u < 4; ++u) *(uint4*)&wv[u * 4] = *(const uint4*)&w[u * 4];
      #pragma unroll
      for (int c = 0; c < 16; ++c) acc1[c] = FDOT2(xv, wv[c], acc1[c]);
    }
    const int j0 = sl * 16;
    #pragma unroll
    for (int c2 = 0; c2 < 8; ++c2) {
      float a = fmaxf(acc1[2 * c2] + bf1[j0 + 2 * c2], 0.f);
      float b = fmaxf(acc1[2 * c2 + 1] + bf1[j0 + 2 * c2 + 1], 0.f);
      y1buf[fr * 65 + sl * 8 + c2] = pack2(a, b);
    }
  }
  __syncthreads();

  // ---------- phase 3: fc2, j in [sl*8, sl*8+8) -> featsh ----------
  {
    float acc2[8];
    #pragma unroll
    for (int c = 0; c < 8; ++c) acc2[c] = 0.f;
    #pragma unroll 2
    for (int k2 = 0; k2 < 64; ++k2) {
      h2 xv = y1buf[fr * 65 + k2];          // scalar LDS read, conflict-free
      const h2* w = wf2 + k2 * 64 + sl * 8;
      h2 wv[8];
      #pragma unroll
      for (int u = 0; u < 2; ++u) *(uint4*)&wv[u * 4] = *(const uint4*)&w[u * 4];
      #pragma unroll
      for (int c = 0; c < 8; ++c) acc2[c] = FDOT2(xv, wv[c], acc2[c]);
    }
    const int j0 = sl * 8;
    #pragma unroll
    for (int c2 = 0; c2 < 4; ++c2) {
      float a = fmaxf(acc2[2 * c2] + bf2[j0 + 2 * c2], 0.f);
      float b = fmaxf(acc2[2 * c2 + 1] + bf2[j0 + 2 * c2 + 1], 0.f);
      featsh[(size_t)(sl * 4 + c2) * GT + g] = pack2(a, b);
    }
  }
}

// ---------------- encoder x-projection + LDS-transposed coalesced gx write ----------
__global__ __launch_bounds__(256, 2) void k_xgatesh(const h2* __restrict__ featsh,
                                                    const h2* __restrict__ wxh,
                                                    const float* __restrict__ br,
                                                    float* __restrict__ gx) {
  __shared__ float lbuf[256 * 68];
  int t  = blockIdx.x >> 2;
  int bq = blockIdx.x & 3;
  int b  = bq * 256 + threadIdx.x;
  int r0 = blockIdx.y * 64;
  float acc[64];
  #pragma unroll
  for (int i = 0; i < 64; ++i) acc[i] = br[r0 + i];
  const h2* xcol = featsh + (size_t)t * 1024 + b;
  #pragma unroll 1
  for (int k2 = 0; k2 < 32; ++k2) {
    h2 xv = xcol[(size_t)k2 * GT];
    const h2* w = wxh + k2 * 512 + r0;
    h2 wv[64];
    #pragma unroll
    for (int u = 0; u < 16; ++u) *(uint4*)&wv[u * 4] = *(const uint4*)&w[u * 4];
    #pragma unroll
    for (int i = 0; i < 64; ++i) acc[i] = FDOT2(xv, wv[i], acc[i]);
  }
  // stage to LDS
  float* lp = lbuf + threadIdx.x * 68;
  #pragma unroll
  for (int u = 0; u < 16; ++u) {
    float4 v = make_float4(acc[4 * u], acc[4 * u + 1], acc[4 * u + 2], acc[4 * u + 3]);
    *(float4*)&lp[u * 4] = v;
  }
  __syncthreads();
  // coalesced writeout
  const int r4 = threadIdx.x & 15;
  const int bb = threadIdx.x >> 4;
  const size_t base = (size_t)t * 524288 + (size_t)(bq * 256) * 512 + r0;
  #pragma unroll
  for (int j = 0; j < 16; ++j) {
    int bl = j * 16 + bb;
    float4 v = *(const float4*)&lbuf[bl * 68 + r4 * 4];
    *(float4*)&gx[base + (size_t)bl * 512 + r4 * 4] = v;
  }
}

// ---------------- fused enc+dec+head: 1 batch/block, register weights ---------------
// 1024 blocks x 512 threads. Thread (kg=tid&1 k-half, rp=(tid>>1)&1 gate-pair,
// g=tid>>2 unit). Each thread owns rows {g*4+rp*2, +1} x 32 k2 = 64 h2 in VGPRs.
// R6 LESSON: launch_bounds(512,4) forced a 64-VGPR cap (compiler treats 2nd arg as
// min BLOCKS/CU: 4 blocks x 8 waves = 8 waves/SIMD -> <=64 VGPR) and spilled wreg
// to scratch (WRITE_SIZE 80MB, 166us). (512,2) = 2 blocks/CU -> <=128 VGPR cap;
// the ~90-VGPR working set fits, and 90<=128 still yields 4 waves/SIMD at runtime.
// Math identical to R6 (verified absmax-equal): 32 sequential k2 dot2 per row +
// one commutative pair-add (shfl_xor 1); gate-pair exchange shfl_xor 2 + select.
__global__ __launch_bounds__(512, 2) void k_seq(
    const float* __restrict__ gx,
    const h2* __restrict__ WENCH, const h2* __restrict__ WDECH,
    const float* __restrict__ bdec,
    const float* __restrict__ ow, const float* __restrict__ ob,
    float* __restrict__ out) {
  const int tid = threadIdx.x;
  const int kg  = tid & 1;            // k-pair half: k2 in [kg*32, kg*32+32)
  const int rp  = (tid >> 1) & 1;     // gate pair: rows g*4 + rp*2 + {0,1}
  const int g   = tid >> 2;           // hidden unit 0..127
  const int b   = blockIdx.x;         // one batch per block

  __shared__ h2 hbufh[2][68];         // [buf][k2] f16 h (one batch)
  __shared__ h2 owl2[12 * 68];

  for (int i = tid; i < 2 * 68; i += 512) ((h2*)hbufh)[i] = pack2(0.f, 0.f);
  for (int i = tid; i < 768; i += 512) {
    int o = i >> 6, k2 = i & 63;
    owl2[o * 68 + k2] = pack2(ow[o * 128 + 2 * k2], ow[o * 128 + 2 * k2 + 1]);
  }
  const float obv = (tid < 12) ? ob[tid] : 0.f;

  // wreg[p][j]: W[k2=kg*32+p][row g*4 + rp*2 + j], j=0,1 -> 64 VGPR
  h2 wreg[32][2];
  #pragma unroll
  for (int p = 0; p < 32; ++p)
    *(uint2*)wreg[p] = *(const uint2*)(WENCH + (size_t)(kg * 32 + p) * 512 + g * 4 + rp * 2);

  float c0 = 0.f;
  __syncthreads();
  int cur = 0;

  // ================= encoder: 32 steps =================
  for (int t = 0; t < TSEQ; ++t) {
    const float4 ga = *(const float4*)(gx + (size_t)t * 524288 + (size_t)b * 512 + g * 4);

    float a0 = 0.f, a1 = 0.f;
    const h2* hp = &hbufh[cur][kg * 32];
    #pragma unroll
    for (int pc = 0; pc < 8; ++pc) {
      h2 hh[4];
      *(uint4*)hh = *(const uint4*)&hp[pc * 4];
      #pragma unroll
      for (int j = 0; j < 4; ++j) {
        const int p = pc * 4 + j;
        a0 = FDOT2(hh[j], wreg[p][0], a0);
        a1 = FDOT2(hh[j], wreg[p][1], a1);
      }
    }
    // reduce across kg (commutative pair-add -> bitwise same as old 2-way split)
    const float D0 = a0 + __shfl_xor(a0, 1, 64);
    const float D1 = a1 + __shfl_xor(a1, 1, 64);
    // exchange gate pairs across rp
    const float e0 = __shfl_xor(D0, 2, 64);
    const float e1 = __shfl_xor(D1, 2, 64);
    const float Di = rp ? e0 : D0;
    const float Df = rp ? e1 : D1;
    const float Dg = rp ? D0 : e0;
    const float Do = rp ? D1 : e1;

    const float gi = Di + ga.x, gf = Df + ga.y, gg = Dg + ga.z, go = Do + ga.w;
    c0 = sigf(gf) * c0 + sigf(gi) * tanhfast(gg);
    const float hn = sigf(go) * tanhfast(c0);
    if ((tid & 3) == 0) {
      _Float16* hf = (_Float16*)&hbufh[cur ^ 1][0];
      hf[g] = (_Float16)hn;
    }
    __syncthreads();
    cur ^= 1;
  }

  // ---- swap in DEC weights (x_in == h => W = W_ih + W_hh, pre-summed) ----
  #pragma unroll
  for (int p = 0; p < 32; ++p)
    *(uint2*)wreg[p] = *(const uint2*)(WDECH + (size_t)(kg * 32 + p) * 512 + g * 4 + rp * 2);
  const float4 bd = *(const float4*)(bdec + g * 4);

  // ================= decoder: 10 steps + fused head =================
  for (int t = 0; t < 10; ++t) {
    float a0 = 0.f, a1 = 0.f;
    const h2* hp = &hbufh[cur][kg * 32];
    #pragma unroll
    for (int pc = 0; pc < 8; ++pc) {
      h2 hh[4];
      *(uint4*)hh = *(const uint4*)&hp[pc * 4];
      #pragma unroll
      for (int j = 0; j < 4; ++j) {
        const int p = pc * 4 + j;
        a0 = FDOT2(hh[j], wreg[p][0], a0);
        a1 = FDOT2(hh[j], wreg[p][1], a1);
      }
    }
    const float D0 = a0 + __shfl_xor(a0, 1, 64);
    const float D1 = a1 + __shfl_xor(a1, 1, 64);
    const float e0 = __shfl_xor(D0, 2, 64);
    const float e1 = __shfl_xor(D1, 2, 64);
    const float Di = rp ? e0 : D0;
    const float Df = rp ? e1 : D1;
    const float Dg = rp ? D0 : e0;
    const float Do = rp ? D1 : e1;

    const float gi = Di + bd.x, gf = Df + bd.y, gg = Dg + bd.z, go = Do + bd.w;
    c0 = sigf(gf) * c0 + sigf(gi) * tanhfast(gg);
    const float hn = sigf(go) * tanhfast(c0);
    if ((tid & 3) == 0) {
      _Float16* hf = (_Float16*)&hbufh[cur ^ 1][0];
      hf[g] = (_Float16)hn;
    }
    __syncthreads();
    cur ^= 1;
    // output head: tid<12 (o = tid), LDS-only reads of new h
    if (tid < 12) {
      const h2* hh = &hbufh[cur][0];
      const h2* wo = &owl2[tid * 68];
      float oacc = obv;
      #pragma unroll
      for (int k2 = 0; k2 < 64; ++k2) oacc = FDOT2(hh[k2], wo[k2], oacc);
      out[b * 120 + t * 12 + tid] = oacc;
    }
  }
}

// ---------------- launch ----------------
extern "C" void kernel_launch(void* const* d_in, const int* in_sizes, int n_in,
                              void* d_out, int out_size, void* d_ws, size_t ws_size,
                              hipStream_t stream) {
  const float* obs  = (const float*)d_in[0];
  const float* c1w  = (const float*)d_in[1];
  const float* c1b  = (const float*)d_in[2];
  const float* c2w  = (const float*)d_in[3];
  const float* c2b  = (const float*)d_in[4];
  const float* f1w  = (const float*)d_in[5];
  const float* f1b  = (const float*)d_in[6];
  const float* g1   = (const float*)d_in[7];
  const float* be1  = (const float*)d_in[8];
  const float* m1   = (const float*)d_in[9];
  const float* v1   = (const float*)d_in[10];
  const float* f2w  = (const float*)d_in[11];
  const float* f2b  = (const float*)d_in[12];
  const float* g2   = (const float*)d_in[13];
  const float* be2  = (const float*)d_in[14];
  const float* m2   = (const float*)d_in[15];
  const float* v2   = (const float*)d_in[16];
  const float* ewih = (const float*)d_in[17];
  const float* ewhh = (const float*)d_in[18];
  const float* eb   = (const float*)d_in[19];
  const float* dwih = (const float*)d_in[20];
  const float* dwhh = (const float*)d_in[21];
  const float* db   = (const float*)d_in[22];
  const float* ow   = (const float*)d_in[23];
  const float* ob   = (const float*)d_in[24];
  float* ws  = (float*)d_ws;
  h2*    wsh = (h2*)d_ws;
  float* out = (float*)d_out;

  // weight prep: 98304 items = 384 blocks x 256
  k_setup<<<384, 256, 0, stream>>>(c1w, c2w, f1w, f1b, g1, be1, m1, v1,
                                   f2w, f2b, g2, be2, m2, v2,
                                   ewih, ewhh, eb, dwih, dwhh, db, ws);
  k_transpose<<<dim3(200, 16), 256, 0, stream>>>(obs, ws + OBS_T);
  k_conv1<<<dim3(128, 25), 256, 0, stream>>>(ws + OBS_T, ws + W_C1, c1b, wsh + POOL1H);
  // fused conv2 + fc1 + fc2: R4 config (best measured)
  k_cfx<<<1024, 256, 0, stream>>>(wsh + POOL1H, wsh + W_C2H, c2b,
                                  wsh + W_F1H, ws + B_F1,
                                  wsh + W_F2H, ws + B_F2, wsh + FEATSH);
  k_xgatesh<<<dim3(128, 8), 256, 0, stream>>>(wsh + FEATSH, wsh + W_ENCXH, ws + B_ENC,
                                              ws + GX);
  // fused encoder + decoder + output head: 1 batch/block, no spill (see k_seq note)
  k_seq<<<1024, 512, 0, stream>>>(ws + GX, wsh + W_ENCHH, wsh + W_DECH,
                                  ws + B_DEC, ow, ob, out);
}

// Round 8
// 386.473 us; speedup vs baseline: 1.2234x; 1.2234x over previous
//
#include <hip/hip_runtime.h>
#include <hip/hip_bf16.h>
#include <hip/hip_fp16.h>

// ---------------- problem constants ----------------
constexpr int GT = 32768;          // B*T frames
constexpr int TSEQ = 32;

typedef _Float16 h2 __attribute__((ext_vector_type(2)));

#if defined(__has_builtin)
#if __has_builtin(__builtin_amdgcn_fdot2)
#define FDOT2(a, b, c) __builtin_amdgcn_fdot2((a), (b), (c), false)
#endif
#endif
#ifndef FDOT2
#define FDOT2(a, b, c) fmaf((float)(a).x, (float)(b).x, fmaf((float)(a).y, (float)(b).y, (c)))
#endif

__device__ __forceinline__ h2 pack2(float a, float b) {
  h2 v; v.x = (_Float16)a; v.y = (_Float16)b; return v;
}

// ---------------- workspace layout (4-byte slots; wsh = h2 view, ws = f32 view) -----
constexpr size_t OBS_T  = 0;
constexpr size_t POOL1H = 13107200;
constexpr size_t FEATSH = 19660800;
constexpr size_t WB     = 26214400;
constexpr size_t W_C1   = WB + 0;           // 576  fp32: conv1 wT [36][16]
constexpr size_t W_C2H  = WB + 576;         // 2304 h2: [(ci2*9+t9)][32 co]
constexpr size_t W_F1H  = WB + 2880;        // 8192 h2: [q=co2*4+pos][128 j], BN folded
constexpr size_t B_F1   = WB + 11072;       // 128 fp32
constexpr size_t W_F2H  = WB + 11200;       // 4096 h2: [k2][64 j], BN folded
constexpr size_t B_F2   = WB + 15296;       // 64 fp32
constexpr size_t W_ENCXH= WB + 15360;       // 16384 h2: [k2][512 r], rows r=u*4+gate
constexpr size_t W_ENCHH= WB + 31744;       // 32768 h2: [k2][512 r]
constexpr size_t B_ENC  = WB + 64512;       // 512 fp32
constexpr size_t W_DECH = WB + 65024;       // 32768 h2: (dec_w_ih+dec_w_hh) [k2][512]
constexpr size_t B_DEC  = WB + 97792;       // 512 fp32

__device__ __forceinline__ float sigf(float x)  { return 1.f / (1.f + __expf(-x)); }
__device__ __forceinline__ float tanhfast(float x) { return 1.f - 2.f / (__expf(2.f * x) + 1.f); }

// ---------------- setup: transpose/fold/f16-pack weights (98304 items) ----------
__global__ __launch_bounds__(256) void k_setup(
    const float* __restrict__ c1w, const float* __restrict__ c2w,
    const float* __restrict__ f1w, const float* __restrict__ f1b,
    const float* __restrict__ g1, const float* __restrict__ be1,
    const float* __restrict__ m1, const float* __restrict__ v1,
    const float* __restrict__ f2w, const float* __restrict__ f2b,
    const float* __restrict__ g2, const float* __restrict__ be2,
    const float* __restrict__ m2, const float* __restrict__ v2,
    const float* __restrict__ ewih, const float* __restrict__ ewhh, const float* __restrict__ eb,
    const float* __restrict__ dwih, const float* __restrict__ dwhh, const float* __restrict__ db,
    float* __restrict__ ws) {
  h2* wsh = (h2*)ws;
  long i = (long)blockIdx.x * 256 + threadIdx.x;
  if (i < 576)  { int c = i & 15, r = i >> 4; ws[W_C1 + i] = c1w[c * 36 + r]; return; }
  i -= 576;
  if (i < 2304) { int co = i & 31, q = i >> 5; int ci2 = q / 9, t9 = q % 9;
    wsh[W_C2H + i] = pack2(c2w[co * 144 + (2 * ci2) * 9 + t9],
                           c2w[co * 144 + (2 * ci2 + 1) * 9 + t9]); return; }
  i -= 2304;
  if (i < 8192) { int j = i & 127, q = i >> 7; int co2 = q >> 2, pos = q & 3;
    float s = g1[j] * rsqrtf(v1[j] + 1e-5f);
    wsh[W_F1H + i] = pack2(f1w[j * 128 + 8 * co2 + pos] * s,
                           f1w[j * 128 + 8 * co2 + 4 + pos] * s); return; }
  i -= 8192;
  if (i < 128) { int j = i; float s = g1[j] * rsqrtf(v1[j] + 1e-5f);
    ws[B_F1 + i] = (f1b[j] - m1[j]) * s + be1[j]; return; }
  i -= 128;
  if (i < 4096) { int j = i & 63, k2 = i >> 6;
    float s = g2[j] * rsqrtf(v2[j] + 1e-5f);
    wsh[W_F2H + i] = pack2(f2w[j * 128 + 2 * k2] * s,
                           f2w[j * 128 + 2 * k2 + 1] * s); return; }
  i -= 4096;
  if (i < 64) { int j = i; float s = g2[j] * rsqrtf(v2[j] + 1e-5f);
    ws[B_F2 + i] = (f2b[j] - m2[j]) * s + be2[j]; return; }
  i -= 64;
  if (i < 16384) { int r = i & 511, k2 = i >> 9;
    int u = r >> 2, gt = r & 3, jr = gt * 128 + u;
    wsh[W_ENCXH + i] = pack2(ewih[jr * 64 + 2 * k2], ewih[jr * 64 + 2 * k2 + 1]); return; }
  i -= 16384;
  if (i < 32768) { int r = i & 511, k2 = i >> 9;
    int u = r >> 2, gt = r & 3, jr = gt * 128 + u;
    wsh[W_ENCHH + i] = pack2(ewhh[jr * 128 + 2 * k2], ewhh[jr * 128 + 2 * k2 + 1]); return; }
  i -= 32768;
  if (i < 512) { int u = i >> 2, gt = i & 3; ws[B_ENC + i] = eb[gt * 128 + u]; return; }
  i -= 512;
  if (i < 32768) { int r = i & 511, k2 = i >> 9;
    int u = r >> 2, gt = r & 3, jr = gt * 128 + u;
    wsh[W_DECH + i] = pack2(dwih[jr * 128 + 2 * k2] + dwhh[jr * 128 + 2 * k2],
                            dwih[jr * 128 + 2 * k2 + 1] + dwhh[jr * 128 + 2 * k2 + 1]); return; }
  i -= 32768;
  if (i < 512) { int u = i >> 2, gt = i & 3; ws[B_DEC + i] = db[gt * 128 + u]; return; }
}

// ---------------- transpose obs [b][tp] -> obsT [p][t][b], float4 loads ----------------
__global__ __launch_bounds__(256) void k_transpose(const float* __restrict__ obs,
                                                   float* __restrict__ obsT) {
  __shared__ float tile[64][65];
  int tp0 = blockIdx.x * 64;
  int b0  = blockIdx.y * 64;
  int q     = threadIdx.x & 15;
  int rbase = threadIdx.x >> 4;
  #pragma unroll
  for (int rr = 0; rr < 4; ++rr) {
    int row = rbase + rr * 16;
    const float4 v = *(const float4*)(obs + (size_t)(b0 + row) * 12800 + tp0 + q * 4);
    tile[row][q * 4 + 0] = v.x;
    tile[row][q * 4 + 1] = v.y;
    tile[row][q * 4 + 2] = v.z;
    tile[row][q * 4 + 3] = v.w;
  }
  __syncthreads();
  int lane = threadIdx.x & 63;
  int grp  = threadIdx.x >> 6;
  for (int cc = 0; cc < 16; ++cc) {
    int col = grp * 16 + cc;
    int tp = tp0 + col;
    int t = tp / 400, p = tp % 400;
    obsT[(size_t)p * GT + t * 1024 + b0 + lane] = tile[lane][col];
  }
}

// ---------------- conv1 (4->16, fp32 math) + relu + maxpool2; writes f16 co-pairs ----
__global__ __launch_bounds__(256) void k_conv1(const float* __restrict__ obsT,
                                               const float* __restrict__ wT,
                                               const float* __restrict__ bias,
                                               h2* __restrict__ pool1h) {
  int g = blockIdx.x * 256 + threadIdx.x;
  int pos = blockIdx.y;
  int py = pos / 5, px = pos % 5;
  float acc[4][16];
  #pragma unroll
  for (int s = 0; s < 4; ++s)
    #pragma unroll
    for (int c = 0; c < 16; ++c) acc[s][c] = 0.f;

  #pragma unroll 1
  for (int ci = 0; ci < 4; ++ci) {
    float p[16];
    #pragma unroll
    for (int r = 0; r < 4; ++r) {
      int iy = 2 * py + r - 1;
      #pragma unroll
      for (int cx = 0; cx < 4; ++cx) {
        int ix = 2 * px + cx - 1;
        bool ok = ((unsigned)iy < 10u) && ((unsigned)ix < 10u);   // wave-uniform
        p[r * 4 + cx] = ok ? obsT[(size_t)(ci * 100 + iy * 10 + ix) * GT + g] : 0.f;
      }
    }
    #pragma unroll
    for (int t9 = 0; t9 < 9; ++t9) {
      int ky = t9 / 3, kx = t9 % 3;
      const float* w = wT + ((ci * 9 + t9) << 4);
      float wv[16];
      #pragma unroll
      for (int c = 0; c < 16; ++c) wv[c] = w[c];
      #pragma unroll
      for (int dy = 0; dy < 2; ++dy)
        #pragma unroll
        for (int dx = 0; dx < 2; ++dx) {
          float xv = p[(dy + ky) * 4 + (dx + kx)];
          #pragma unroll
          for (int c = 0; c < 16; ++c)
            acc[dy * 2 + dx][c] = fmaf(wv[c], xv, acc[dy * 2 + dx][c]);
        }
    }
  }
  float m[16];
  #pragma unroll
  for (int c = 0; c < 16; ++c) {
    float v = fmaxf(fmaxf(acc[0][c], acc[1][c]), fmaxf(acc[2][c], acc[3][c]));
    m[c] = fmaxf(v + bias[c], 0.f);
  }
  #pragma unroll
  for (int c2 = 0; c2 < 8; ++c2)
    pool1h[(size_t)(c2 * 25 + pos) * GT + g] = pack2(m[2 * c2], m[2 * c2 + 1]);
}

// ---------------- fused conv2 + fc1 + fc2 (R4 config — best measured: 99us) ----------
__global__ __launch_bounds__(256, 4) void k_cfx(
    const h2* __restrict__ pool1h,
    const h2* __restrict__ wc2, const float* __restrict__ c2b,
    const h2* __restrict__ wf1, const float* __restrict__ bf1,
    const h2* __restrict__ wf2, const float* __restrict__ bf2,
    h2* __restrict__ featsh) {
  const int tid = threadIdx.x;
  const int fr  = tid & 31;
  const int sl  = tid >> 5;           // 0..7
  const int g   = blockIdx.x * 32 + fr;
  const int pos = sl & 3;             // pooled pos 0..3
  const int ho  = sl >> 2;            // co half (16 channels)

  __shared__ h2 xbuf[32 * 65];      // conv2 out pairs, [fr][q=co2*4+pos], stride 65
  __shared__ h2 y1buf[32 * 65];     // fc1 out pairs,   [fr][jp],          stride 65

  // ---------- phase 1: conv2 at pooled pos, co-half ho ----------
  const int py = pos >> 1, px = pos & 1;
  const h2 hz = pack2(0.f, 0.f);
  float acc[4][16];
  #pragma unroll
  for (int s = 0; s < 4; ++s)
    #pragma unroll
    for (int c = 0; c < 16; ++c) acc[s][c] = 0.f;

  #pragma unroll 1
  for (int ci2 = 0; ci2 < 8; ++ci2) {
    h2 p[16];
    #pragma unroll
    for (int r = 0; r < 4; ++r) {
      int iy = 2 * py + r - 1;
      #pragma unroll
      for (int cx = 0; cx < 4; ++cx) {
        int ix = 2 * px + cx - 1;
        bool ok = ((unsigned)iy < 5u) && ((unsigned)ix < 5u);   // half-wave-uniform
        p[r * 4 + cx] = ok ? pool1h[(size_t)(ci2 * 25 + iy * 5 + ix) * GT + g] : hz;
      }
    }
    #pragma unroll
    for (int t9 = 0; t9 < 9; ++t9) {
      int ky = t9 / 3, kx = t9 % 3;
      const h2* w = wc2 + (ci2 * 9 + t9) * 32 + ho * 16;
      h2 wv[16];
      #pragma unroll
      for (int u = 0; u < 4; ++u) *(uint4*)&wv[u * 4] = *(const uint4*)&w[u * 4];
      #pragma unroll
      for (int dy = 0; dy < 2; ++dy)
        #pragma unroll
        for (int dx = 0; dx < 2; ++dx) {
          h2 xv = p[(dy + ky) * 4 + (dx + kx)];
          #pragma unroll
          for (int c = 0; c < 16; ++c)
            acc[dy * 2 + dx][c] = FDOT2(xv, wv[c], acc[dy * 2 + dx][c]);
        }
    }
  }
  #pragma unroll
  for (int c2 = 0; c2 < 8; ++c2) {
    float va = fmaxf(fmaxf(acc[0][2 * c2], acc[1][2 * c2]),
                     fmaxf(acc[2][2 * c2], acc[3][2 * c2]));
    float vb = fmaxf(fmaxf(acc[0][2 * c2 + 1], acc[1][2 * c2 + 1]),
                     fmaxf(acc[2][2 * c2 + 1], acc[3][2 * c2 + 1]));
    float a = fmaxf(va + c2b[ho * 16 + 2 * c2], 0.f);
    float b = fmaxf(vb + c2b[ho * 16 + 2 * c2 + 1], 0.f);
    int q = (ho * 8 + c2) * 4 + pos;       // co2*4 + pos
    xbuf[fr * 65 + q] = pack2(a, b);
  }
  __syncthreads();

  // ---------- phase 2: fc1, j in [sl*16, sl*16+16) ----------
  {
    float acc1[16];
    #pragma unroll
    for (int c = 0; c < 16; ++c) acc1[c] = 0.f;
    #pragma unroll 2
    for (int q = 0; q < 64; ++q) {
      h2 xv = xbuf[fr * 65 + q];            // scalar LDS read, conflict-free
      const h2* w = wf1 + q * 128 + sl * 16;
      h2 wv[16];
      #pragma unroll
      for (int u = 0; u < 4; ++u) *(uint4*)&wv[u * 4] = *(const uint4*)&w[u * 4];
      #pragma unroll
      for (int c = 0; c < 16; ++c) acc1[c] = FDOT2(xv, wv[c], acc1[c]);
    }
    const int j0 = sl * 16;
    #pragma unroll
    for (int c2 = 0; c2 < 8; ++c2) {
      float a = fmaxf(acc1[2 * c2] + bf1[j0 + 2 * c2], 0.f);
      float b = fmaxf(acc1[2 * c2 + 1] + bf1[j0 + 2 * c2 + 1], 0.f);
      y1buf[fr * 65 + sl * 8 + c2] = pack2(a, b);
    }
  }
  __syncthreads();

  // ---------- phase 3: fc2, j in [sl*8, sl*8+8) -> featsh ----------
  {
    float acc2[8];
    #pragma unroll
    for (int c = 0; c < 8; ++c) acc2[c] = 0.f;
    #pragma unroll 2
    for (int k2 = 0; k2 < 64; ++k2) {
      h2 xv = y1buf[fr * 65 + k2];          // scalar LDS read, conflict-free
      const h2* w = wf2 + k2 * 64 + sl * 8;
      h2 wv[8];
      #pragma unroll
      for (int u = 0; u < 2; ++u) *(uint4*)&wv[u * 4] = *(const uint4*)&w[u * 4];
      #pragma unroll
      for (int c = 0; c < 8; ++c) acc2[c] = FDOT2(xv, wv[c], acc2[c]);
    }
    const int j0 = sl * 8;
    #pragma unroll
    for (int c2 = 0; c2 < 4; ++c2) {
      float a = fmaxf(acc2[2 * c2] + bf2[j0 + 2 * c2], 0.f);
      float b = fmaxf(acc2[2 * c2 + 1] + bf2[j0 + 2 * c2 + 1], 0.f);
      featsh[(size_t)(sl * 4 + c2) * GT + g] = pack2(a, b);
    }
  }
}

// ---------------- fused xproj + enc + dec + head -------------------------------------
// 256 blocks x 512 threads (1 block/CU), R1's proven k_seq8 step structure restored
// (4 batches/block, 8 dot-chains/thread, 98us measured) + x-projection fused in:
//  - feats for the block's 4 batches staged to LDS once (18KB)
//  - gx computed IN-KERNEL into LDS in two t-halves of 16 (132KB buffer), bias +
//    32 sequential k2 FDOT2 per gate in k_xgatesh's exact order -> bitwise-same gx
//  - per-step ga/gb reads become LDS reads (was global, ~300-600cy L3)
//  - eliminates k_xgatesh kernel + 67MB gx write + 35MB gx fetch entirely
// wreg is RELOADED from L2 after each xproj phase so it is not live across it
// (R6 spill lesson: keep live VGPR under the 128 cap; verify WRITE_SIZE stays ~0).
__global__ __launch_bounds__(512, 2) void k_seqf(
    const h2* __restrict__ featsh,
    const h2* __restrict__ WXH, const float* __restrict__ br,
    const h2* __restrict__ WENCH, const h2* __restrict__ WDECH,
    const float* __restrict__ bdec,
    const float* __restrict__ ow, const float* __restrict__ ob,
    float* __restrict__ out) {
  const int tid = threadIdx.x;
  const int bl2 = tid & 1;            // batch-pair selector (batches bl2*2, bl2*2+1)
  const int kg  = (tid >> 1) & 1;     // k-pair half: k2 in [kg*32, kg*32+32)
  const int g   = tid >> 2;           // hidden unit 0..127 (rows g*4..g*4+3)
  // xproj mapping
  const int bx  = tid & 3;            // batch 0..3
  const int rw  = tid >> 2;           // row-quad 0..127 (rows rw*4..+3)
  const int gb0 = blockIdx.x * 4;

  __shared__ float gxl[16 * 2064];    // [tl 16][b 4][516] f32 gates   (132096 B)
  __shared__ h2    featl[32 * 144];   // [t 32][bx 4][36] h2 feats     ( 18432 B)
  __shared__ h2    hbufh[2][4 * 68];  // h double-buffer               (  2176 B)
  __shared__ h2    owl2[12 * 68];     // head weights                  (  3264 B)

  for (int i = tid; i < 2 * 4 * 68; i += 512) ((h2*)hbufh)[i] = pack2(0.f, 0.f);
  for (int i = tid; i < 768; i += 512) {
    int o = i >> 6, k2 = i & 63;
    owl2[o * 68 + k2] = pack2(ow[o * 128 + 2 * k2], ow[o * 128 + 2 * k2 + 1]);
  }
  const float obv = (tid < 48) ? ob[tid >> 2] : 0.f;

  // stage feats for this block's 4 batches: featl[t][bx][j2]
  for (int i = tid; i < 4096; i += 512) {
    int j2 = i & 31, bxs = (i >> 5) & 3, t = i >> 7;
    featl[t * 144 + bxs * 36 + j2] = featsh[(size_t)j2 * GT + t * 1024 + gb0 + bxs];
  }

  float c0 = 0.f, c1 = 0.f;
  int cur = 0;
  h2 wreg[32][4];

  #pragma unroll 1
  for (int half = 0; half < 2; ++half) {
    __syncthreads();   // half0: featl ready; half1: step-15 readers done with gxl

    // ---- xproj: gxl[tl][bx][r] = br[r] + sum_k2 dot2(feats, Wx) (k2 order 0..31) ----
    const float4 bias4 = *(const float4*)(br + rw * 4);
    #pragma unroll 1
    for (int t8 = 0; t8 < 2; ++t8) {
      float acc[8][4];
      #pragma unroll
      for (int tt = 0; tt < 8; ++tt) {
        acc[tt][0] = bias4.x; acc[tt][1] = bias4.y;
        acc[tt][2] = bias4.z; acc[tt][3] = bias4.w;
      }
      #pragma unroll 1
      for (int k2q = 0; k2q < 8; ++k2q) {
        h2 wv[4][4];
        #pragma unroll
        for (int q = 0; q < 4; ++q)
          *(uint4*)wv[q] = *(const uint4*)(WXH + (size_t)(k2q * 4 + q) * 512 + rw * 4);
        #pragma unroll
        for (int tt = 0; tt < 8; ++tt) {
          const int t = half * 16 + t8 * 8 + tt;
          h2 xq[4];
          *(uint4*)xq = *(const uint4*)&featl[t * 144 + bx * 36 + k2q * 4];
          #pragma unroll
          for (int q = 0; q < 4; ++q) {
            acc[tt][0] = FDOT2(xq[q], wv[q][0], acc[tt][0]);
            acc[tt][1] = FDOT2(xq[q], wv[q][1], acc[tt][1]);
            acc[tt][2] = FDOT2(xq[q], wv[q][2], acc[tt][2]);
            acc[tt][3] = FDOT2(xq[q], wv[q][3], acc[tt][3]);
          }
        }
      }
      #pragma unroll
      for (int tt = 0; tt < 8; ++tt)
        *(float4*)&gxl[(t8 * 8 + tt) * 2064 + bx * 516 + rw * 4] =
            make_float4(acc[tt][0], acc[tt][1], acc[tt][2], acc[tt][3]);
    }

    // ---- (re)load encoder h-weights (keeps them dead across xproj: no spill) ----
    #pragma unroll
    for (int p = 0; p < 32; ++p)
      *(uint4*)wreg[p] = *(const uint4*)(WENCH + (size_t)(kg * 32 + p) * 512 + g * 4);
    __syncthreads();

    // ---- 16 encoder steps (R1 k_seq8 body, ga/gb from LDS) ----
    for (int tl = 0; tl < 16; ++tl) {
      const float4 ga = *(const float4*)&gxl[tl * 2064 + (bl2 * 2 + 0) * 516 + g * 4];
      const float4 gb = *(const float4*)&gxl[tl * 2064 + (bl2 * 2 + 1) * 516 + g * 4];

      float acc[8];
      #pragma unroll
      for (int r = 0; r < 8; ++r) acc[r] = 0.f;

      #pragma unroll
      for (int b = 0; b < 2; ++b) {
        const h2* hp = &hbufh[cur][(bl2 * 2 + b) * 68 + kg * 32];
        #pragma unroll
        for (int pc = 0; pc < 8; ++pc) {
          h2 hh[4];
          *(uint4*)hh = *(const uint4*)&hp[pc * 4];
          #pragma unroll
          for (int j = 0; j < 4; ++j) {
            const int p = pc * 4 + j;
            acc[b * 4 + 0] = FDOT2(hh[j], wreg[p][0], acc[b * 4 + 0]);
            acc[b * 4 + 1] = FDOT2(hh[j], wreg[p][1], acc[b * 4 + 1]);
            acc[b * 4 + 2] = FDOT2(hh[j], wreg[p][2], acc[b * 4 + 2]);
            acc[b * 4 + 3] = FDOT2(hh[j], wreg[p][3], acc[b * 4 + 3]);
          }
        }
      }
      float D[8];
      #pragma unroll
      for (int r = 0; r < 8; ++r) D[r] = acc[r] + __shfl_xor(acc[r], 2, 64);

      const float gi0 = D[0] + ga.x, gf0 = D[1] + ga.y, gg0 = D[2] + ga.z, go0 = D[3] + ga.w;
      const float gi1 = D[4] + gb.x, gf1 = D[5] + gb.y, gg1 = D[6] + gb.z, go1 = D[7] + gb.w;
      c0 = sigf(gf0) * c0 + sigf(gi0) * tanhfast(gg0);
      c1 = sigf(gf1) * c1 + sigf(gi1) * tanhfast(gg1);
      const float hn0 = sigf(go0) * tanhfast(c0);
      const float hn1 = sigf(go1) * tanhfast(c1);
      if (kg == 0) {
        _Float16* hf = (_Float16*)&hbufh[cur ^ 1][0];
        hf[(bl2 * 2 + 0) * 136 + g] = (_Float16)hn0;
        hf[(bl2 * 2 + 1) * 136 + g] = (_Float16)hn1;
      }
      __syncthreads();
      cur ^= 1;
    }
  }

  // ---- swap in DEC weights (x_in == h => W = W_ih + W_hh, pre-summed) ----
  #pragma unroll
  for (int p = 0; p < 32; ++p)
    *(uint4*)wreg[p] = *(const uint4*)(WDECH + (size_t)(kg * 32 + p) * 512 + g * 4);
  const float4 bd = *(const float4*)(bdec + g * 4);

  // ================= decoder: 10 steps + fused head =================
  for (int t = 0; t < 10; ++t) {
    float acc[8];
    #pragma unroll
    for (int r = 0; r < 8; ++r) acc[r] = 0.f;

    #pragma unroll
    for (int b = 0; b < 2; ++b) {
      const h2* hp = &hbufh[cur][(bl2 * 2 + b) * 68 + kg * 32];
      #pragma unroll
      for (int pc = 0; pc < 8; ++pc) {
        h2 hh[4];
        *(uint4*)hh = *(const uint4*)&hp[pc * 4];
        #pragma unroll
        for (int j = 0; j < 4; ++j) {
          const int p = pc * 4 + j;
          acc[b * 4 + 0] = FDOT2(hh[j], wreg[p][0], acc[b * 4 + 0]);
          acc[b * 4 + 1] = FDOT2(hh[j], wreg[p][1], acc[b * 4 + 1]);
          acc[b * 4 + 2] = FDOT2(hh[j], wreg[p][2], acc[b * 4 + 2]);
          acc[b * 4 + 3] = FDOT2(hh[j], wreg[p][3], acc[b * 4 + 3]);
        }
      }
    }
    float D[8];
    #pragma unroll
    for (int r = 0; r < 8; ++r) D[r] = acc[r] + __shfl_xor(acc[r], 2, 64);

    const float gi0 = D[0] + bd.x, gf0 = D[1] + bd.y, gg0 = D[2] + bd.z, go0 = D[3] + bd.w;
    const float gi1 = D[4] + bd.x, gf1 = D[5] + bd.y, gg1 = D[6] + bd.z, go1 = D[7] + bd.w;
    c0 = sigf(gf0) * c0 + sigf(gi0) * tanhfast(gg0);
    c1 = sigf(gf1) * c1 + sigf(gi1) * tanhfast(gg1);
    const float hn0 = sigf(go0) * tanhfast(c0);
    const float hn1 = sigf(go1) * tanhfast(c1);
    if (kg == 0) {
      _Float16* hf = (_Float16*)&hbufh[cur ^ 1][0];
      hf[(bl2 * 2 + 0) * 136 + g] = (_Float16)hn0;
      hf[(bl2 * 2 + 1) * 136 + g] = (_Float16)hn1;
    }
    __syncthreads();
    cur ^= 1;
    // output head: tid<48 (o = tid>>2, bh = tid&3), LDS-only reads of new h
    if (tid < 48) {
      const int o  = tid >> 2;
      const int bh = tid & 3;
      const h2* hh = &hbufh[cur][bh * 68];
      const h2* wo = &owl2[o * 68];
      float oacc = obv;
      #pragma unroll
      for (int k2 = 0; k2 < 64; ++k2) oacc = FDOT2(hh[k2], wo[k2], oacc);
      out[(blockIdx.x * 4 + bh) * 120 + t * 12 + o] = oacc;
    }
  }
}

// ---------------- launch ----------------
extern "C" void kernel_launch(void* const* d_in, const int* in_sizes, int n_in,
                              void* d_out, int out_size, void* d_ws, size_t ws_size,
                              hipStream_t stream) {
  const float* obs  = (const float*)d_in[0];
  const float* c1w  = (const float*)d_in[1];
  const float* c1b  = (const float*)d_in[2];
  const float* c2w  = (const float*)d_in[3];
  const float* c2b  = (const float*)d_in[4];
  const float* f1w  = (const float*)d_in[5];
  const float* f1b  = (const float*)d_in[6];
  const float* g1   = (const float*)d_in[7];
  const float* be1  = (const float*)d_in[8];
  const float* m1   = (const float*)d_in[9];
  const float* v1   = (const float*)d_in[10];
  const float* f2w  = (const float*)d_in[11];
  const float* f2b  = (const float*)d_in[12];
  const float* g2   = (const float*)d_in[13];
  const float* be2  = (const float*)d_in[14];
  const float* m2   = (const float*)d_in[15];
  const float* v2   = (const float*)d_in[16];
  const float* ewih = (const float*)d_in[17];
  const float* ewhh = (const float*)d_in[18];
  const float* eb   = (const float*)d_in[19];
  const float* dwih = (const float*)d_in[20];
  const float* dwhh = (const float*)d_in[21];
  const float* db   = (const float*)d_in[22];
  const float* ow   = (const float*)d_in[23];
  const float* ob   = (const float*)d_in[24];
  float* ws  = (float*)d_ws;
  h2*    wsh = (h2*)d_ws;
  float* out = (float*)d_out;

  // weight prep: 98304 items = 384 blocks x 256
  k_setup<<<384, 256, 0, stream>>>(c1w, c2w, f1w, f1b, g1, be1, m1, v1,
                                   f2w, f2b, g2, be2, m2, v2,
                                   ewih, ewhh, eb, dwih, dwhh, db, ws);
  k_transpose<<<dim3(200, 16), 256, 0, stream>>>(obs, ws + OBS_T);
  k_conv1<<<dim3(128, 25), 256, 0, stream>>>(ws + OBS_T, ws + W_C1, c1b, wsh + POOL1H);
  // fused conv2 + fc1 + fc2: R4 config (best measured)
  k_cfx<<<1024, 256, 0, stream>>>(wsh + POOL1H, wsh + W_C2H, c2b,
                                  wsh + W_F1H, ws + B_F1,
                                  wsh + W_F2H, ws + B_F2, wsh + FEATSH);
  // fused x-projection + encoder + decoder + head (k_xgatesh eliminated)
  k_seqf<<<256, 512, 0, stream>>>(wsh + FEATSH, wsh + W_ENCXH, ws + B_ENC,
                                  wsh + W_ENCHH, wsh + W_DECH,
                                  ws + B_DEC, ow, ob, out);
}